// Round 3
// baseline (316.012 us; speedup 1.0000x reference)
//
#include <hip/hip_runtime.h>
#include <hip/hip_cooperative_groups.h>

namespace cg = cooperative_groups;

#define NSEQ   2048
#define HEADS  16
#define DIM    64
#define BATCH  2
#define SCALE  0.125f      // 1/sqrt(64)

// Workspace: tree nodes, global index g in [NSEQ, 2*NSEQ-2), slot = g - NSEQ,
// layout [b][slot][h][d]. NSEQ == WSSLOTS => slot == (g & 2047).
#define WSSLOTS 2048
#define WSELEMS ((size_t)BATCH * WSSLOTS * HEADS * DIM)
#define ROWF4   (DIM / 4)              // 16 float4 per row
#define HSTRIDE (HEADS * ROWF4)        // float4 stride between rows (n or slot)

__device__ __forceinline__ int level_offset(int j) {
    return (j == 0) ? 0 : (2 * NSEQ - ((2 * NSEQ) >> j));
}

__device__ __forceinline__ float dot4(float4 a, float4 b) {
    return a.x * b.x + a.y * b.y + a.z * b.z + a.w * b.w;
}

__device__ __forceinline__ void reduce3_16(float& a, float& b, float& c) {
#pragma unroll
    for (int m = 1; m < 16; m <<= 1) {
        a += __shfl_xor(a, m, 64);
        b += __shfl_xor(b, m, 64);
        c += __shfl_xor(c, m, 64);
    }
}

// Parent = 3-way softmax mix of {mean, child0, child1}; 16 lanes per parent,
// each lane owns a float4 of the 64 dims. Reference fp32 semantics.
__device__ __forceinline__ void make_parent4(float4 k0, float4 k1, float4 v0, float4 v1,
                                             float4& kc, float4& vc) {
    float4 kp, vp;
    kp.x = 0.5f * (k0.x + k1.x); kp.y = 0.5f * (k0.y + k1.y);
    kp.z = 0.5f * (k0.z + k1.z); kp.w = 0.5f * (k0.w + k1.w);
    vp.x = 0.5f * (v0.x + v1.x); vp.y = 0.5f * (v0.y + v1.y);
    vp.z = 0.5f * (v0.z + v1.z); vp.w = 0.5f * (v0.w + v1.w);
    float ss = dot4(kp, kp), sa = dot4(kp, k0), sb = dot4(kp, k1);
    reduce3_16(ss, sa, sb);
    ss *= SCALE; sa *= SCALE; sb *= SCALE;
    float mx = fmaxf(ss, fmaxf(sa, sb));
    float es = __expf(ss - mx), ea = __expf(sa - mx), eb = __expf(sb - mx);
    float inv = 1.0f / (es + ea + eb + 1e-9f);
    es *= inv; ea *= inv; eb *= inv;
    kc.x = es * kp.x + ea * k0.x + eb * k1.x;
    kc.y = es * kp.y + ea * k0.y + eb * k1.y;
    kc.z = es * kp.z + ea * k0.z + eb * k1.z;
    kc.w = es * kp.w + ea * k0.w + eb * k1.w;
    vc.x = es * vp.x + ea * v0.x + eb * v1.x;
    vc.y = es * vp.y + ea * v0.y + eb * v1.y;
    vc.z = es * vp.z + ea * v0.z + eb * v1.z;
    vc.w = es * vp.w + ea * v0.w + eb * v1.w;
}

// ---- Phase A: tree levels 1..6 for one 64-leaf chunk. 1024 tasks (b,h,c).
// LDS ping-pong: odd levels -> rows [0,32), even levels -> rows [32,48).
__device__ __forceinline__ void phaseA(const float4* __restrict__ K4,
                                       const float4* __restrict__ V4,
                                       float4* __restrict__ Kw4,
                                       float4* __restrict__ Vw4,
                                       float4* Kb, float4* Vb, int bid) {
    int c = bid & 31;
    int h = (bid >> 5) & 15;
    int b = bid >> 9;
    int wave = threadIdx.x >> 6;
    int lane = threadIdx.x & 63;
    int g = lane >> 4, t = lane & 15;

#pragma unroll
    for (int j = 1; j <= 6; ++j) {
        int P = 64 >> j;
        int curOff  = (j & 1) ? 0 : 32;
        int prevOff = (j & 1) ? 32 : 0;
        for (int i0 = 0; i0 < P; i0 += 16) {
            int p = i0 + wave * 4 + g;
            if (p < P) {
                float4 k0, k1, v0, v1;
                if (j == 1) {
                    int n0 = c * 64 + 2 * p;
                    const float4* Kr = K4 + ((size_t)((b * NSEQ + n0) * HEADS + h)) * ROWF4;
                    const float4* Vr = V4 + ((size_t)((b * NSEQ + n0) * HEADS + h)) * ROWF4;
                    k0 = Kr[t]; k1 = Kr[HSTRIDE + t];
                    v0 = Vr[t]; v1 = Vr[HSTRIDE + t];
                } else {
                    int s = (prevOff + 2 * p) * ROWF4 + t;
                    k0 = Kb[s]; k1 = Kb[s + ROWF4];
                    v0 = Vb[s]; v1 = Vb[s + ROWF4];
                }
                float4 kc, vc;
                make_parent4(k0, k1, v0, v1, kc, vc);
                Kb[(curOff + p) * ROWF4 + t] = kc;
                Vb[(curOff + p) * ROWF4 + t] = vc;
                int slot = level_offset(j) - NSEQ + c * P + p;
                size_t widx = ((size_t)((b * WSSLOTS + slot) * HEADS + h)) * ROWF4 + t;
                Kw4[widx] = kc;
                Vw4[widx] = vc;
            }
        }
        __syncthreads();
    }
}

// ---- Phase B: tree levels 7..10 for one (b,h). 32 tasks.
// slots: lvl6 children at 1984+; outputs lvl7->2016+, lvl8->2032+, lvl9->2040+, lvl10->2044+.
__device__ __forceinline__ void phaseB(float4* __restrict__ Kw4,
                                       float4* __restrict__ Vw4,
                                       float4* Kb, float4* Vb, int bid) {
    if (bid >= BATCH * HEADS) return;
    int h = bid & 15, b = bid >> 4;
    int lane = threadIdx.x & 63;
    int g = lane >> 4, t = lane & 15;
    int p = (threadIdx.x >> 6) * 4 + g;          // 0..15

    // level 7: 16 parents, children = level-6 nodes in ws
    {
        size_t cb = ((size_t)((b * WSSLOTS + 1984 + 2 * p) * HEADS + h)) * ROWF4 + t;
        float4 k0 = Kw4[cb], k1 = Kw4[cb + HSTRIDE];
        float4 v0 = Vw4[cb], v1 = Vw4[cb + HSTRIDE];
        float4 kc, vc;
        make_parent4(k0, k1, v0, v1, kc, vc);
        Kb[p * ROWF4 + t] = kc;  Vb[p * ROWF4 + t] = vc;
        size_t w = ((size_t)((b * WSSLOTS + 2016 + p) * HEADS + h)) * ROWF4 + t;
        Kw4[w] = kc;  Vw4[w] = vc;
    }
    __syncthreads();
    // level 8: 8 parents, children LDS rows [0,16) -> rows [16,24)
    if (p < 8) {
        int s = (2 * p) * ROWF4 + t;
        float4 k0 = Kb[s], k1 = Kb[s + ROWF4];
        float4 v0 = Vb[s], v1 = Vb[s + ROWF4];
        float4 kc, vc;
        make_parent4(k0, k1, v0, v1, kc, vc);
        Kb[(16 + p) * ROWF4 + t] = kc;  Vb[(16 + p) * ROWF4 + t] = vc;
        size_t w = ((size_t)((b * WSSLOTS + 2032 + p) * HEADS + h)) * ROWF4 + t;
        Kw4[w] = kc;  Vw4[w] = vc;
    }
    __syncthreads();
    // level 9: 4 parents, children rows [16,24) -> rows [24,28)
    if (p < 4) {
        int s = (16 + 2 * p) * ROWF4 + t;
        float4 k0 = Kb[s], k1 = Kb[s + ROWF4];
        float4 v0 = Vb[s], v1 = Vb[s + ROWF4];
        float4 kc, vc;
        make_parent4(k0, k1, v0, v1, kc, vc);
        Kb[(24 + p) * ROWF4 + t] = kc;  Vb[(24 + p) * ROWF4 + t] = vc;
        size_t w = ((size_t)((b * WSSLOTS + 2040 + p) * HEADS + h)) * ROWF4 + t;
        Kw4[w] = kc;  Vw4[w] = vc;
    }
    __syncthreads();
    // level 10: 2 parents, children rows [24,28) -> ws only
    if (p < 2) {
        int s = (24 + 2 * p) * ROWF4 + t;
        float4 k0 = Kb[s], k1 = Kb[s + ROWF4];
        float4 v0 = Vb[s], v1 = Vb[s + ROWF4];
        float4 kc, vc;
        make_parent4(k0, k1, v0, v1, kc, vc);
        size_t w = ((size_t)((b * WSSLOTS + 2044 + p) * HEADS + h)) * ROWF4 + t;
        Kw4[w] = kc;  Vw4[w] = vc;
    }
}

// ---- Phase C: attention. One wave = all 16 heads of one (b,n), looping 4
// head-groups. Node rows computed once; cols 0,1 are leaves, 2..11 tree slots.
__device__ __forceinline__ void phaseC(const float4* __restrict__ Q4,
                                       const float4* __restrict__ K4,
                                       const float4* __restrict__ V4,
                                       const float4* __restrict__ Kw4,
                                       const float4* __restrict__ Vw4,
                                       float4* __restrict__ O4, int bid) {
    int wv = bid * 4 + (threadIdx.x >> 6);   // 0..4095 over (b,n)
    int lane = threadIdx.x & 63;
    int g = lane >> 4, t = lane & 15;
    int n = wv & (NSEQ - 1);
    int b = wv >> 11;

    unsigned active = 1u | (((unsigned)n & 0x7FFu) << 1);

    int row0 = (b * NSEQ + n) * HSTRIDE;          // self leaf (also Q/out row)
    int row1 = (b * NSEQ + (n ^ 1)) * HSTRIDE;    // sibling leaf
    int rowt[10];                                  // tree rows, cols 2..11
#pragma unroll
    for (int l = 2; l < 12; ++l) {
        int j = l - 1;
        int gn = level_offset(j) + ((n >> j) ^ 1);   // always >= NSEQ
        rowt[l - 2] = (b * WSSLOTS + (gn - NSEQ)) * HSTRIDE;
    }

    for (int hg = 0; hg < 4; ++hg) {
        int hoff = (hg * 4 + g) * ROWF4 + t;
        float4 q4 = Q4[row0 + hoff];

        float s[12];
        s[0] = dot4(q4, K4[row0 + hoff]);
        s[1] = dot4(q4, K4[row1 + hoff]);
#pragma unroll
        for (int l = 2; l < 12; ++l) s[l] = dot4(q4, Kw4[rowt[l - 2] + hoff]);

#pragma unroll
        for (int m = 1; m < 16; m <<= 1) {
#pragma unroll
            for (int l = 0; l < 12; ++l) s[l] += __shfl_xor(s[l], m, 64);
        }

        float mx = -3.402823466e+38f;
#pragma unroll
        for (int l = 0; l < 12; ++l) {
            s[l] *= SCALE;
            if (active & (1u << l)) mx = fmaxf(mx, s[l]);
        }
        float sum = 0.f;
#pragma unroll
        for (int l = 0; l < 12; ++l) {
            float e = (active & (1u << l)) ? __expf(s[l] - mx) : 0.f;
            s[l] = e;
            sum += e;
        }
        float inv = 1.0f / sum;

        float4 o = make_float4(0.f, 0.f, 0.f, 0.f);
        {
            float4 v = V4[row0 + hoff];
            o.x += s[0] * v.x; o.y += s[0] * v.y; o.z += s[0] * v.z; o.w += s[0] * v.w;
            v = V4[row1 + hoff];
            o.x += s[1] * v.x; o.y += s[1] * v.y; o.z += s[1] * v.z; o.w += s[1] * v.w;
        }
#pragma unroll
        for (int l = 2; l < 12; ++l) {
            float4 v = Vw4[rowt[l - 2] + hoff];
            o.x += s[l] * v.x; o.y += s[l] * v.y; o.z += s[l] * v.z; o.w += s[l] * v.w;
        }
        O4[row0 + hoff] = make_float4(o.x * inv, o.y * inv, o.z * inv, o.w * inv);
    }
}

// ---- Fused cooperative kernel: 1024 blocks x 256 threads, 24 KB LDS.
__global__ __launch_bounds__(256, 4) void fused(const float* __restrict__ Q,
                                                const float* __restrict__ K,
                                                const float* __restrict__ V,
                                                float* __restrict__ Kw,
                                                float* __restrict__ Vw,
                                                float* __restrict__ out) {
    __shared__ float4 Kb[48 * ROWF4];
    __shared__ float4 Vb[48 * ROWF4];
    const float4* Q4 = (const float4*)Q;
    const float4* K4 = (const float4*)K;
    const float4* V4 = (const float4*)V;
    float4* Kw4 = (float4*)Kw;
    float4* Vw4 = (float4*)Vw;
    float4* O4  = (float4*)out;
    cg::grid_group grid = cg::this_grid();

    phaseA(K4, V4, Kw4, Vw4, Kb, Vb, blockIdx.x);
    grid.sync();
    phaseB(Kw4, Vw4, Kb, Vb, blockIdx.x);
    grid.sync();
    phaseC(Q4, K4, V4, Kw4, Vw4, O4, blockIdx.x);
}

// ---- Fallback wrappers (used only if cooperative launch is unavailable).
__global__ __launch_bounds__(256, 4) void treeA_k(const float* K, const float* V,
                                                  float* Kw, float* Vw) {
    __shared__ float4 Kb[48 * ROWF4];
    __shared__ float4 Vb[48 * ROWF4];
    phaseA((const float4*)K, (const float4*)V, (float4*)Kw, (float4*)Vw, Kb, Vb, blockIdx.x);
}
__global__ __launch_bounds__(256, 4) void treeB_k(float* Kw, float* Vw) {
    __shared__ float4 Kb[48 * ROWF4];
    __shared__ float4 Vb[48 * ROWF4];
    phaseB((float4*)Kw, (float4*)Vw, Kb, Vb, blockIdx.x);
}
__global__ __launch_bounds__(256, 4) void attn_k(const float* Q, const float* K, const float* V,
                                                 const float* Kw, const float* Vw, float* out) {
    phaseC((const float4*)Q, (const float4*)K, (const float4*)V,
           (const float4*)Kw, (const float4*)Vw, (float4*)out, blockIdx.x);
}

extern "C" void kernel_launch(void* const* d_in, const int* in_sizes, int n_in,
                              void* d_out, int out_size, void* d_ws, size_t ws_size,
                              hipStream_t stream) {
    const float* Q = (const float*)d_in[0];
    const float* K = (const float*)d_in[1];
    const float* V = (const float*)d_in[2];
    float* out = (float*)d_out;
    float* Kw = (float*)d_ws;              // 16.78 MiB
    float* Vw = Kw + WSELEMS;              // 16.78 MiB

    void* args[] = { (void*)&Q, (void*)&K, (void*)&V,
                     (void*)&Kw, (void*)&Vw, (void*)&out };
    hipError_t e = hipLaunchCooperativeKernel(reinterpret_cast<void*>(fused),
                                              dim3(1024), dim3(256), args, 0, stream);
    if (e != hipSuccess) {
        (void)hipGetLastError();   // clear sticky error; deterministic fallback
        treeA_k<<<1024, 256, 0, stream>>>(K, V, Kw, Vw);
        treeB_k<<<BATCH * HEADS, 256, 0, stream>>>(Kw, Vw);
        attn_k<<<1024, 256, 0, stream>>>(Q, K, V, Kw, Vw, out);
    }
}

// Round 4
// 128.873 us; speedup vs baseline: 2.4521x; 2.4521x over previous
//
#include <hip/hip_runtime.h>

#define NSEQ   2048
#define HEADS  16
#define DIM    64
#define BATCH  2
#define SCALE  0.125f      // 1/sqrt(64)

// Workspace: tree nodes, global index g in [NSEQ, 2*NSEQ-2), slot = g - NSEQ,
// layout [b][slot][h][d].
#define WSSLOTS 2048
#define WSELEMS ((size_t)BATCH * WSSLOTS * HEADS * DIM)
#define ROWF4   (DIM / 4)              // 16 float4 per row
#define HSTRIDE (HEADS * ROWF4)        // float4 stride between rows (n or slot)

__device__ __forceinline__ int level_offset(int j) {
    return (j == 0) ? 0 : (2 * NSEQ - ((2 * NSEQ) >> j));
}

__device__ __forceinline__ float dot4(float4 a, float4 b) {
    return a.x * b.x + a.y * b.y + a.z * b.z + a.w * b.w;
}

__device__ __forceinline__ void reduce3_16(float& a, float& b, float& c) {
#pragma unroll
    for (int m = 1; m < 16; m <<= 1) {
        a += __shfl_xor(a, m, 64);
        b += __shfl_xor(b, m, 64);
        c += __shfl_xor(c, m, 64);
    }
}

// Parent = 3-way softmax mix of {mean, child0, child1}; 16 lanes per parent,
// each lane owns a float4 of the 64 dims. Reference fp32 semantics.
__device__ __forceinline__ void make_parent4(float4 k0, float4 k1, float4 v0, float4 v1,
                                             float4& kc, float4& vc) {
    float4 kp, vp;
    kp.x = 0.5f * (k0.x + k1.x); kp.y = 0.5f * (k0.y + k1.y);
    kp.z = 0.5f * (k0.z + k1.z); kp.w = 0.5f * (k0.w + k1.w);
    vp.x = 0.5f * (v0.x + v1.x); vp.y = 0.5f * (v0.y + v1.y);
    vp.z = 0.5f * (v0.z + v1.z); vp.w = 0.5f * (v0.w + v1.w);
    float ss = dot4(kp, kp), sa = dot4(kp, k0), sb = dot4(kp, k1);
    reduce3_16(ss, sa, sb);
    ss *= SCALE; sa *= SCALE; sb *= SCALE;
    float mx = fmaxf(ss, fmaxf(sa, sb));
    float es = __expf(ss - mx), ea = __expf(sa - mx), eb = __expf(sb - mx);
    float inv = 1.0f / (es + ea + eb + 1e-9f);
    es *= inv; ea *= inv; eb *= inv;
    kc.x = es * kp.x + ea * k0.x + eb * k1.x;
    kc.y = es * kp.y + ea * k0.y + eb * k1.y;
    kc.z = es * kp.z + ea * k0.z + eb * k1.z;
    kc.w = es * kp.w + ea * k0.w + eb * k1.w;
    vc.x = es * vp.x + ea * v0.x + eb * v1.x;
    vc.y = es * vp.y + ea * v0.y + eb * v1.y;
    vc.z = es * vp.z + ea * v0.z + eb * v1.z;
    vc.w = es * vp.w + ea * v0.w + eb * v1.w;
}

// ---- Kernel A: tree levels 1..6 for one 64-leaf chunk. 1024 blocks (b,h,c).
// LDS ping-pong: odd levels -> rows [0,32), even levels -> rows [32,48).
__global__ __launch_bounds__(256) void tree_low(const float* __restrict__ K,
                                                const float* __restrict__ V,
                                                float* __restrict__ Kw,
                                                float* __restrict__ Vw) {
    __shared__ float4 Kb[48 * ROWF4];
    __shared__ float4 Vb[48 * ROWF4];
    const float4* K4 = (const float4*)K;
    const float4* V4 = (const float4*)V;
    float4* Kw4 = (float4*)Kw;
    float4* Vw4 = (float4*)Vw;

    int bid = blockIdx.x;
    int c = bid & 31;
    int h = (bid >> 5) & 15;
    int b = bid >> 9;
    int wave = threadIdx.x >> 6;
    int lane = threadIdx.x & 63;
    int g = lane >> 4, t = lane & 15;

#pragma unroll
    for (int j = 1; j <= 6; ++j) {
        int P = 64 >> j;
        int curOff  = (j & 1) ? 0 : 32;
        int prevOff = (j & 1) ? 32 : 0;
        for (int i0 = 0; i0 < P; i0 += 16) {
            int p = i0 + wave * 4 + g;
            if (p < P) {
                float4 k0, k1, v0, v1;
                if (j == 1) {
                    int n0 = c * 64 + 2 * p;
                    const float4* Kr = K4 + ((size_t)((b * NSEQ + n0) * HEADS + h)) * ROWF4;
                    const float4* Vr = V4 + ((size_t)((b * NSEQ + n0) * HEADS + h)) * ROWF4;
                    k0 = Kr[t]; k1 = Kr[HSTRIDE + t];
                    v0 = Vr[t]; v1 = Vr[HSTRIDE + t];
                } else {
                    int s = (prevOff + 2 * p) * ROWF4 + t;
                    k0 = Kb[s]; k1 = Kb[s + ROWF4];
                    v0 = Vb[s]; v1 = Vb[s + ROWF4];
                }
                float4 kc, vc;
                make_parent4(k0, k1, v0, v1, kc, vc);
                Kb[(curOff + p) * ROWF4 + t] = kc;
                Vb[(curOff + p) * ROWF4 + t] = vc;
                int slot = level_offset(j) - NSEQ + c * P + p;
                size_t widx = ((size_t)((b * WSSLOTS + slot) * HEADS + h)) * ROWF4 + t;
                Kw4[widx] = kc;
                Vw4[widx] = vc;
            }
        }
        __syncthreads();
    }
}

// ---- Kernel B: tree levels 7..10 for one (b,h). 32 blocks.
// slots: lvl6 at 1984+, lvl7->2016+, lvl8->2032+, lvl9->2040+, lvl10->2044+.
__global__ __launch_bounds__(256) void tree_top(float* __restrict__ Kw,
                                                float* __restrict__ Vw) {
    __shared__ float4 Kb[28 * ROWF4];
    __shared__ float4 Vb[28 * ROWF4];
    float4* Kw4 = (float4*)Kw;
    float4* Vw4 = (float4*)Vw;

    int h = blockIdx.x & 15, b = blockIdx.x >> 4;
    int lane = threadIdx.x & 63;
    int g = lane >> 4, t = lane & 15;
    int p = (threadIdx.x >> 6) * 4 + g;          // 0..15

    // level 7: 16 parents, children = level-6 nodes in ws
    {
        size_t cb = ((size_t)((b * WSSLOTS + 1984 + 2 * p) * HEADS + h)) * ROWF4 + t;
        float4 k0 = Kw4[cb], k1 = Kw4[cb + HSTRIDE];
        float4 v0 = Vw4[cb], v1 = Vw4[cb + HSTRIDE];
        float4 kc, vc;
        make_parent4(k0, k1, v0, v1, kc, vc);
        Kb[p * ROWF4 + t] = kc;  Vb[p * ROWF4 + t] = vc;
        size_t w = ((size_t)((b * WSSLOTS + 2016 + p) * HEADS + h)) * ROWF4 + t;
        Kw4[w] = kc;  Vw4[w] = vc;
    }
    __syncthreads();
    // level 8: 8 parents, children LDS rows [0,16) -> rows [16,24)
    if (p < 8) {
        int s = (2 * p) * ROWF4 + t;
        float4 k0 = Kb[s], k1 = Kb[s + ROWF4];
        float4 v0 = Vb[s], v1 = Vb[s + ROWF4];
        float4 kc, vc;
        make_parent4(k0, k1, v0, v1, kc, vc);
        Kb[(16 + p) * ROWF4 + t] = kc;  Vb[(16 + p) * ROWF4 + t] = vc;
        size_t w = ((size_t)((b * WSSLOTS + 2032 + p) * HEADS + h)) * ROWF4 + t;
        Kw4[w] = kc;  Vw4[w] = vc;
    }
    __syncthreads();
    // level 9: 4 parents, children rows [16,24) -> rows [24,28)
    if (p < 4) {
        int s = (16 + 2 * p) * ROWF4 + t;
        float4 k0 = Kb[s], k1 = Kb[s + ROWF4];
        float4 v0 = Vb[s], v1 = Vb[s + ROWF4];
        float4 kc, vc;
        make_parent4(k0, k1, v0, v1, kc, vc);
        Kb[(24 + p) * ROWF4 + t] = kc;  Vb[(24 + p) * ROWF4 + t] = vc;
        size_t w = ((size_t)((b * WSSLOTS + 2040 + p) * HEADS + h)) * ROWF4 + t;
        Kw4[w] = kc;  Vw4[w] = vc;
    }
    __syncthreads();
    // level 10: 2 parents, children rows [24,28) -> ws only
    if (p < 2) {
        int s = (24 + 2 * p) * ROWF4 + t;
        float4 k0 = Kb[s], k1 = Kb[s + ROWF4];
        float4 v0 = Vb[s], v1 = Vb[s + ROWF4];
        float4 kc, vc;
        make_parent4(k0, k1, v0, v1, kc, vc);
        size_t w = ((size_t)((b * WSSLOTS + 2044 + p) * HEADS + h)) * ROWF4 + t;
        Kw4[w] = kc;  Vw4[w] = vc;
    }
}

// ---- Kernel C: attention. One wave = 4 heads (4*(w&3)+g) of one (b,n).
// All 12 K rows loaded into registers BEFORE use (12-deep MLP), then dots;
// all 12 V rows issued before the shuffle phase so their latency hides under
// the reduction + softmax. 16384 waves.
__global__ __launch_bounds__(256) void attn(const float* __restrict__ Q,
                                            const float* __restrict__ K,
                                            const float* __restrict__ V,
                                            const float* __restrict__ Kw,
                                            const float* __restrict__ Vw,
                                            float* __restrict__ out) {
    const float4* Q4 = (const float4*)Q;
    const float4* K4 = (const float4*)K;
    const float4* V4 = (const float4*)V;
    const float4* Kw4 = (const float4*)Kw;
    const float4* Vw4 = (const float4*)Vw;
    float4* O4 = (float4*)out;

    int w = blockIdx.x * 4 + (threadIdx.x >> 6);   // wave id over B*N*(H/4)
    int lane = threadIdx.x & 63;
    int g = lane >> 4;                             // head sub-index
    int t = lane & 15;                             // float4 index within row
    int h = (w & 3) * 4 + g;
    int n = (w >> 2) & (NSEQ - 1);
    int b = w >> 13;

    // per-wave node rows (int float4-offsets; all < 2^21)
    int row0 = (b * NSEQ + n) * HSTRIDE;           // self leaf / Q / out
    int row1 = (b * NSEQ + (n ^ 1)) * HSTRIDE;     // sibling leaf
    int rowt[10];
#pragma unroll
    for (int l = 2; l < 12; ++l) {
        int j = l - 1;
        int slot = level_offset(j) - NSEQ + ((n >> j) ^ 1);
        rowt[l - 2] = (b * WSSLOTS + slot) * HSTRIDE;
    }
    int hoff = h * ROWF4 + t;

    // column l active iff l==0 or bit (l-1) of n set
    unsigned active = 1u | (((unsigned)n & 0x7FFu) << 1);

    float4 q4 = Q4[row0 + hoff];

    // batch all K loads (MLP), then dot
    float4 k[12];
    k[0] = K4[row0 + hoff];
    k[1] = K4[row1 + hoff];
#pragma unroll
    for (int l = 2; l < 12; ++l) k[l] = Kw4[rowt[l - 2] + hoff];

    float s[12];
#pragma unroll
    for (int l = 0; l < 12; ++l) s[l] = dot4(q4, k[l]);

    // issue V loads now; latency hides under shuffles + softmax
    float4 v[12];
    v[0] = V4[row0 + hoff];
    v[1] = V4[row1 + hoff];
#pragma unroll
    for (int l = 2; l < 12; ++l) v[l] = Vw4[rowt[l - 2] + hoff];

#pragma unroll
    for (int m = 1; m < 16; m <<= 1) {
#pragma unroll
        for (int l = 0; l < 12; ++l) s[l] += __shfl_xor(s[l], m, 64);
    }

    float mx = -3.402823466e+38f;
#pragma unroll
    for (int l = 0; l < 12; ++l) {
        s[l] *= SCALE;
        if (active & (1u << l)) mx = fmaxf(mx, s[l]);
    }
    float sum = 0.f;
#pragma unroll
    for (int l = 0; l < 12; ++l) {
        float e = (active & (1u << l)) ? __expf(s[l] - mx) : 0.f;
        s[l] = e;
        sum += e;
    }
    float inv = 1.0f / sum;

    float4 o = make_float4(0.f, 0.f, 0.f, 0.f);
#pragma unroll
    for (int l = 0; l < 12; ++l) {
        o.x += s[l] * v[l].x; o.y += s[l] * v[l].y;
        o.z += s[l] * v[l].z; o.w += s[l] * v[l].w;
    }
    O4[row0 + hoff] = make_float4(o.x * inv, o.y * inv, o.z * inv, o.w * inv);
}

extern "C" void kernel_launch(void* const* d_in, const int* in_sizes, int n_in,
                              void* d_out, int out_size, void* d_ws, size_t ws_size,
                              hipStream_t stream) {
    const float* Q = (const float*)d_in[0];
    const float* K = (const float*)d_in[1];
    const float* V = (const float*)d_in[2];
    float* out = (float*)d_out;
    float* Kw = (float*)d_ws;              // 16.78 MiB
    float* Vw = Kw + WSELEMS;              // 16.78 MiB

    tree_low<<<1024, 256, 0, stream>>>(K, V, Kw, Vw);
    tree_top<<<BATCH * HEADS, 256, 0, stream>>>(Kw, Vw);
    attn<<<(BATCH * NSEQ * (HEADS / 4)) / 4, 256, 0, stream>>>(Q, K, V, Kw, Vw, out);
}

// Round 6
// 124.243 us; speedup vs baseline: 2.5435x; 1.0373x over previous
//
#include <hip/hip_runtime.h>

#define NSEQ   2048
#define HEADS  16
#define DIM    64
#define BATCH  2
#define SCALE  0.125f      // 1/sqrt(64)

// Workspace: tree nodes, global index g in [NSEQ, 2*NSEQ-2), slot = g - NSEQ,
// layout [b][slot][h][d]. Invariant: parent(level_offset(j)+i) = level_offset(j+1)+i/2.
// Slot map: lvl1 0..1023, lvl2 1024.., lvl3 1536.., lvl4 1792.., lvl5 1920..,
// lvl6 1984.., lvl7 2016.., lvl8 2032.., lvl9 2040.., lvl10 2044,2045.
#define WSSLOTS 2048
#define WSELEMS ((size_t)BATCH * WSSLOTS * HEADS * DIM)
#define ROWF4   (DIM / 4)              // 16 float4 per row
#define HSTRIDE (HEADS * ROWF4)        // float4 stride between rows (n or slot)

__device__ __forceinline__ int level_offset(int j) {
    return (j == 0) ? 0 : (2 * NSEQ - ((2 * NSEQ) >> j));
}

__device__ __forceinline__ float dot4(float4 a, float4 b) {
    return a.x * b.x + a.y * b.y + a.z * b.z + a.w * b.w;
}

__device__ __forceinline__ void reduce3_16(float& a, float& b, float& c) {
#pragma unroll
    for (int m = 1; m < 16; m <<= 1) {
        a += __shfl_xor(a, m, 64);
        b += __shfl_xor(b, m, 64);
        c += __shfl_xor(c, m, 64);
    }
}

__device__ __forceinline__ void reduce6_16(float& a, float& b, float& c,
                                           float& d, float& e, float& f) {
#pragma unroll
    for (int m = 1; m < 16; m <<= 1) {
        a += __shfl_xor(a, m, 64);
        b += __shfl_xor(b, m, 64);
        c += __shfl_xor(c, m, 64);
        d += __shfl_xor(d, m, 64);
        e += __shfl_xor(e, m, 64);
        f += __shfl_xor(f, m, 64);
    }
}

// Parent = 3-way softmax mix of {mean, child0, child1}; 16 lanes / parent.
__device__ __forceinline__ void make_parent4(float4 k0, float4 k1, float4 v0, float4 v1,
                                             float4& kc, float4& vc) {
    float4 kp, vp;
    kp.x = 0.5f * (k0.x + k1.x); kp.y = 0.5f * (k0.y + k1.y);
    kp.z = 0.5f * (k0.z + k1.z); kp.w = 0.5f * (k0.w + k1.w);
    vp.x = 0.5f * (v0.x + v1.x); vp.y = 0.5f * (v0.y + v1.y);
    vp.z = 0.5f * (v0.z + v1.z); vp.w = 0.5f * (v0.w + v1.w);
    float ss = dot4(kp, kp), sa = dot4(kp, k0), sb = dot4(kp, k1);
    reduce3_16(ss, sa, sb);
    ss *= SCALE; sa *= SCALE; sb *= SCALE;
    float mx = fmaxf(ss, fmaxf(sa, sb));
    float es = __expf(ss - mx), ea = __expf(sa - mx), eb = __expf(sb - mx);
    float inv = 1.0f / (es + ea + eb + 1e-9f);
    es *= inv; ea *= inv; eb *= inv;
    kc.x = es * kp.x + ea * k0.x + eb * k1.x;
    kc.y = es * kp.y + ea * k0.y + eb * k1.y;
    kc.z = es * kp.z + ea * k0.z + eb * k1.z;
    kc.w = es * kp.w + ea * k0.w + eb * k1.w;
    vc.x = es * vp.x + ea * v0.x + eb * v1.x;
    vc.y = es * vp.y + ea * v0.y + eb * v1.y;
    vc.z = es * vp.z + ea * v0.z + eb * v1.z;
    vc.w = es * vp.w + ea * v0.w + eb * v1.w;
}

// Two independent sibling mixes with an interleaved 6-value butterfly (ILP).
__device__ __forceinline__ void make_parent_pair4(const float4* k, const float4* v,
                                                  float4& ka, float4& va,
                                                  float4& kb, float4& vb) {
    float4 kpa, vpa, kpb, vpb;
    kpa.x = 0.5f * (k[0].x + k[1].x); kpa.y = 0.5f * (k[0].y + k[1].y);
    kpa.z = 0.5f * (k[0].z + k[1].z); kpa.w = 0.5f * (k[0].w + k[1].w);
    vpa.x = 0.5f * (v[0].x + v[1].x); vpa.y = 0.5f * (v[0].y + v[1].y);
    vpa.z = 0.5f * (v[0].z + v[1].z); vpa.w = 0.5f * (v[0].w + v[1].w);
    kpb.x = 0.5f * (k[2].x + k[3].x); kpb.y = 0.5f * (k[2].y + k[3].y);
    kpb.z = 0.5f * (k[2].z + k[3].z); kpb.w = 0.5f * (k[2].w + k[3].w);
    vpb.x = 0.5f * (v[2].x + v[3].x); vpb.y = 0.5f * (v[2].y + v[3].y);
    vpb.z = 0.5f * (v[2].z + v[3].z); vpb.w = 0.5f * (v[2].w + v[3].w);
    float ssa = dot4(kpa, kpa), saa = dot4(kpa, k[0]), sba = dot4(kpa, k[1]);
    float ssb = dot4(kpb, kpb), sab = dot4(kpb, k[2]), sbb = dot4(kpb, k[3]);
    reduce6_16(ssa, saa, sba, ssb, sab, sbb);
    ssa *= SCALE; saa *= SCALE; sba *= SCALE;
    ssb *= SCALE; sab *= SCALE; sbb *= SCALE;
    float mxa = fmaxf(ssa, fmaxf(saa, sba));
    float mxb = fmaxf(ssb, fmaxf(sab, sbb));
    float esa = __expf(ssa - mxa), eaa = __expf(saa - mxa), eba = __expf(sba - mxa);
    float esb = __expf(ssb - mxb), eab = __expf(sab - mxb), ebb = __expf(sbb - mxb);
    float iva = 1.0f / (esa + eaa + eba + 1e-9f);
    float ivb = 1.0f / (esb + eab + ebb + 1e-9f);
    esa *= iva; eaa *= iva; eba *= iva;
    esb *= ivb; eab *= ivb; ebb *= ivb;
    ka.x = esa * kpa.x + eaa * k[0].x + eba * k[1].x;
    ka.y = esa * kpa.y + eaa * k[0].y + eba * k[1].y;
    ka.z = esa * kpa.z + eaa * k[0].z + eba * k[1].z;
    ka.w = esa * kpa.w + eaa * k[0].w + eba * k[1].w;
    va.x = esa * vpa.x + eaa * v[0].x + eba * v[1].x;
    va.y = esa * vpa.y + eaa * v[0].y + eba * v[1].y;
    va.z = esa * vpa.z + eaa * v[0].z + eba * v[1].z;
    va.w = esa * vpa.w + eaa * v[0].w + eba * v[1].w;
    kb.x = esb * kpb.x + eab * k[2].x + ebb * k[3].x;
    kb.y = esb * kpb.y + eab * k[2].y + ebb * k[3].y;
    kb.z = esb * kpb.z + eab * k[2].z + ebb * k[3].z;
    kb.w = esb * kpb.w + eab * k[2].w + ebb * k[3].w;
    vb.x = esb * vpb.x + eab * v[2].x + ebb * v[3].x;
    vb.y = esb * vpb.y + eab * v[2].y + ebb * v[3].y;
    vb.z = esb * vpb.z + eab * v[2].z + ebb * v[3].z;
    vb.w = esb * vpb.w + eab * v[2].w + ebb * v[3].w;
}

// 4-ary consolidation step: 4 child rows -> 2 parents (stored) + 1 grandparent.
__device__ __forceinline__ void quad_step(const float4* k, const float4* v,
                                          float4* Kw4, float4* Vw4,
                                          size_t pRow0, size_t gRow,   // float4 base offsets (+t)
                                          int t,
                                          float4& kg, float4& vg) {
    float4 ka, va, kb, vb;
    make_parent_pair4(k, v, ka, va, kb, vb);
    Kw4[pRow0 + t] = ka;            Vw4[pRow0 + t] = va;
    Kw4[pRow0 + HSTRIDE + t] = kb;  Vw4[pRow0 + HSTRIDE + t] = vb;
    make_parent4(ka, kb, va, vb, kg, vg);
    Kw4[gRow + t] = kg;             Vw4[gRow + t] = vg;
}

// ---- Kernel A: tree levels 1..6 for one 64-leaf chunk. 1024 blocks (b,h,c).
// 3 rounds of 4-ary consolidation, 2 barriers.
__global__ __launch_bounds__(256) void tree_low(const float* __restrict__ K,
                                                const float* __restrict__ V,
                                                float* __restrict__ Kw,
                                                float* __restrict__ Vw) {
    __shared__ float4 Kb[20 * ROWF4];   // rows [0,16): lvl2 ; rows [16,20): lvl4
    __shared__ float4 Vb[20 * ROWF4];
    const float4* K4 = (const float4*)K;
    const float4* V4 = (const float4*)V;
    float4* Kw4 = (float4*)Kw;
    float4* Vw4 = (float4*)Vw;

    int bid = blockIdx.x;
    int c = bid & 31;
    int h = (bid >> 5) & 15;
    int b = bid >> 9;
    int lane = threadIdx.x & 63;
    int gg = (threadIdx.x >> 6) * 4 + (lane >> 4);   // group 0..15
    int t = lane & 15;

    size_t wsBase = (size_t)(b * WSSLOTS) * HSTRIDE + h * ROWF4;  // + slot*HSTRIDE + t

    // Round A: 16 groups, 4 leaves each -> lvl1 pair + lvl2 node
    {
        int n0 = c * 64 + 4 * gg;
        const float4* Kr = K4 + ((size_t)((b * NSEQ + n0) * HEADS + h)) * ROWF4;
        const float4* Vr = V4 + ((size_t)((b * NSEQ + n0) * HEADS + h)) * ROWF4;
        float4 k[4], v[4];
#pragma unroll
        for (int j = 0; j < 4; ++j) { k[j] = Kr[j * HSTRIDE + t]; v[j] = Vr[j * HSTRIDE + t]; }
        int s1 = c * 32 + 2 * gg;          // lvl1 slots s1, s1+1
        int s2 = 1024 + c * 16 + gg;       // lvl2 slot
        float4 kg, vg;
        quad_step(k, v, Kw4, Vw4, wsBase + (size_t)s1 * HSTRIDE,
                  wsBase + (size_t)s2 * HSTRIDE, t, kg, vg);
        Kb[gg * ROWF4 + t] = kg;  Vb[gg * ROWF4 + t] = vg;
    }
    __syncthreads();
    // Round B: groups 0..3, lvl2 rows -> lvl3 pair + lvl4 node
    if (gg < 4) {
        float4 k[4], v[4];
#pragma unroll
        for (int j = 0; j < 4; ++j) {
            k[j] = Kb[(4 * gg + j) * ROWF4 + t];
            v[j] = Vb[(4 * gg + j) * ROWF4 + t];
        }
        int s3 = 1536 + c * 8 + 2 * gg;
        int s4 = 1792 + c * 4 + gg;
        float4 kg, vg;
        quad_step(k, v, Kw4, Vw4, wsBase + (size_t)s3 * HSTRIDE,
                  wsBase + (size_t)s4 * HSTRIDE, t, kg, vg);
        Kb[(16 + gg) * ROWF4 + t] = kg;  Vb[(16 + gg) * ROWF4 + t] = vg;
    }
    __syncthreads();
    // Round C: group 0, lvl4 rows -> lvl5 pair + lvl6 node
    if (gg == 0) {
        float4 k[4], v[4];
#pragma unroll
        for (int j = 0; j < 4; ++j) {
            k[j] = Kb[(16 + j) * ROWF4 + t];
            v[j] = Vb[(16 + j) * ROWF4 + t];
        }
        int s5 = 1920 + c * 2;
        int s6 = 1984 + c;
        float4 kg, vg;
        quad_step(k, v, Kw4, Vw4, wsBase + (size_t)s5 * HSTRIDE,
                  wsBase + (size_t)s6 * HSTRIDE, t, kg, vg);
    }
}

// ---- Kernel B: tree levels 7..10 for one (b,h). 32 blocks, 2 rounds, 1 barrier.
__global__ __launch_bounds__(256) void tree_top(float* __restrict__ Kw,
                                                float* __restrict__ Vw) {
    __shared__ float4 Kb[8 * ROWF4];    // lvl8 nodes
    __shared__ float4 Vb[8 * ROWF4];
    float4* Kw4 = (float4*)Kw;
    float4* Vw4 = (float4*)Vw;

    int h = blockIdx.x & 15, b = blockIdx.x >> 4;
    int lane = threadIdx.x & 63;
    int gg = (threadIdx.x >> 6) * 4 + (lane >> 4);
    int t = lane & 15;
    size_t wsBase = (size_t)(b * WSSLOTS) * HSTRIDE + h * ROWF4;

    // Round A: groups 0..7: 4 lvl6 rows -> lvl7 pair + lvl8 node
    if (gg < 8) {
        float4 k[4], v[4];
#pragma unroll
        for (int j = 0; j < 4; ++j) {
            size_t r = wsBase + (size_t)(1984 + 4 * gg + j) * HSTRIDE + t;
            k[j] = Kw4[r]; v[j] = Vw4[r];
        }
        int s7 = 2016 + 2 * gg;
        int s8 = 2032 + gg;
        float4 kg, vg;
        quad_step(k, v, Kw4, Vw4, wsBase + (size_t)s7 * HSTRIDE,
                  wsBase + (size_t)s8 * HSTRIDE, t, kg, vg);
        Kb[gg * ROWF4 + t] = kg;  Vb[gg * ROWF4 + t] = vg;
    }
    __syncthreads();
    // Round B: groups 0..1: 4 lvl8 rows -> lvl9 pair + lvl10 node
    if (gg < 2) {
        float4 k[4], v[4];
#pragma unroll
        for (int j = 0; j < 4; ++j) {
            k[j] = Kb[(4 * gg + j) * ROWF4 + t];
            v[j] = Vb[(4 * gg + j) * ROWF4 + t];
        }
        int s9  = 2040 + 2 * gg;
        int s10 = 2044 + gg;
        float4 kg, vg;
        quad_step(k, v, Kw4, Vw4, wsBase + (size_t)s9 * HSTRIDE,
                  wsBase + (size_t)s10 * HSTRIDE, t, kg, vg);
    }
}

// ---- Kernel C: attention. One wave = 4 heads of one (b,n). 4096 blocks.
// XCD swizzle (bijective over 4096): blocks land round-robin on XCDs by
// bid&7, so give XCD k the contiguous 512-query span -> uncle rows stay in
// one XCD's L2 instead of being replicated 8x.
__global__ __launch_bounds__(256) void attn(const float* __restrict__ Q,
                                            const float* __restrict__ K,
                                            const float* __restrict__ V,
                                            const float* __restrict__ Kw,
                                            const float* __restrict__ Vw,
                                            float* __restrict__ out) {
    const float4* Q4 = (const float4*)Q;
    const float4* K4 = (const float4*)K;
    const float4* V4 = (const float4*)V;
    const float4* Kw4 = (const float4*)Kw;
    const float4* Vw4 = (const float4*)Vw;
    float4* O4 = (float4*)out;

    int bid = blockIdx.x;                              // 0..4095
    int vbid = ((bid & 7) << 9) | (bid >> 3);          // bijective XCD remap
    int w = vbid * 4 + (threadIdx.x >> 6);             // wave id over B*N*(H/4)
    int lane = threadIdx.x & 63;
    int g = lane >> 4;
    int t = lane & 15;
    int h = (w & 3) * 4 + g;
    int n = (w >> 2) & (NSEQ - 1);
    int b = w >> 13;

    int row0 = (b * NSEQ + n) * HSTRIDE;               // self leaf / Q / out
    int row1 = (b * NSEQ + (n ^ 1)) * HSTRIDE;         // sibling leaf
    int rowt[10];
#pragma unroll
    for (int l = 2; l < 12; ++l) {
        int j = l - 1;
        int slot = level_offset(j) - NSEQ + ((n >> j) ^ 1);
        rowt[l - 2] = (b * WSSLOTS + slot) * HSTRIDE;
    }
    int hoff = h * ROWF4 + t;

    unsigned active = 1u | (((unsigned)n & 0x7FFu) << 1);

    float4 q4 = Q4[row0 + hoff];

    float4 k[12];
    k[0] = K4[row0 + hoff];
    k[1] = K4[row1 + hoff];
#pragma unroll
    for (int l = 2; l < 12; ++l) k[l] = Kw4[rowt[l - 2] + hoff];

    float s[12];
#pragma unroll
    for (int l = 0; l < 12; ++l) s[l] = dot4(q4, k[l]);

    float4 v[12];
    v[0] = V4[row0 + hoff];
    v[1] = V4[row1 + hoff];
#pragma unroll
    for (int l = 2; l < 12; ++l) v[l] = Vw4[rowt[l - 2] + hoff];

#pragma unroll
    for (int m = 1; m < 16; m <<= 1) {
#pragma unroll
        for (int l = 0; l < 12; ++l) s[l] += __shfl_xor(s[l], m, 64);
    }

    float mx = -3.402823466e+38f;
#pragma unroll
    for (int l = 0; l < 12; ++l) {
        s[l] *= SCALE;
        if (active & (1u << l)) mx = fmaxf(mx, s[l]);
    }
    float sum = 0.f;
#pragma unroll
    for (int l = 0; l < 12; ++l) {
        float e = (active & (1u << l)) ? __expf(s[l] - mx) : 0.f;
        s[l] = e;
        sum += e;
    }
    float inv = 1.0f / sum;

    float4 o = make_float4(0.f, 0.f, 0.f, 0.f);
#pragma unroll
    for (int l = 0; l < 12; ++l) {
        o.x += s[l] * v[l].x; o.y += s[l] * v[l].y;
        o.z += s[l] * v[l].z; o.w += s[l] * v[l].w;
    }
    O4[row0 + hoff] = make_float4(o.x * inv, o.y * inv, o.z * inv, o.w * inv);
}

extern "C" void kernel_launch(void* const* d_in, const int* in_sizes, int n_in,
                              void* d_out, int out_size, void* d_ws, size_t ws_size,
                              hipStream_t stream) {
    const float* Q = (const float*)d_in[0];
    const float* K = (const float*)d_in[1];
    const float* V = (const float*)d_in[2];
    float* out = (float*)d_out;
    float* Kw = (float*)d_ws;              // 16.78 MiB
    float* Vw = Kw + WSELEMS;              // 16.78 MiB

    tree_low<<<1024, 256, 0, stream>>>(K, V, Kw, Vw);
    tree_top<<<BATCH * HEADS, 256, 0, stream>>>(Kw, Vw);
    attn<<<(BATCH * NSEQ * (HEADS / 4)) / 4, 256, 0, stream>>>(Q, K, V, Kw, Vw, out);
}

// Round 7
// 117.605 us; speedup vs baseline: 2.6871x; 1.0564x over previous
//
#include <hip/hip_runtime.h>

#define NSEQ   2048
#define HEADS  16
#define DIM    64
#define BATCH  2
#define SCALE  0.125f      // 1/sqrt(64)

// Workspace: tree nodes, global index g in [NSEQ, 2*NSEQ-2), slot = g - NSEQ,
// layout [b][slot][h][d]. Invariant: parent(level_offset(j)+i) = level_offset(j+1)+i/2.
// Slot map: lvl1 0..1023, lvl2 1024.., lvl3 1536.., lvl4 1792.., lvl5 1920..,
// lvl6 1984.., lvl7 2016.., lvl8 2032.., lvl9 2040.., lvl10 2044,2045.
#define WSSLOTS 2048
#define WSELEMS ((size_t)BATCH * WSSLOTS * HEADS * DIM)
#define ROWF4   (DIM / 4)              // 16 float4 per row
#define HSTRIDE (HEADS * ROWF4)        // float4 stride between rows (n or slot)

__device__ __forceinline__ int level_offset(int j) {
    return (j == 0) ? 0 : (2 * NSEQ - ((2 * NSEQ) >> j));
}

__device__ __forceinline__ float dot4(float4 a, float4 b) {
    return a.x * b.x + a.y * b.y + a.z * b.z + a.w * b.w;
}

__device__ __forceinline__ void reduce3_16(float& a, float& b, float& c) {
#pragma unroll
    for (int m = 1; m < 16; m <<= 1) {
        a += __shfl_xor(a, m, 64);
        b += __shfl_xor(b, m, 64);
        c += __shfl_xor(c, m, 64);
    }
}

__device__ __forceinline__ void reduce6_16(float& a, float& b, float& c,
                                           float& d, float& e, float& f) {
#pragma unroll
    for (int m = 1; m < 16; m <<= 1) {
        a += __shfl_xor(a, m, 64);
        b += __shfl_xor(b, m, 64);
        c += __shfl_xor(c, m, 64);
        d += __shfl_xor(d, m, 64);
        e += __shfl_xor(e, m, 64);
        f += __shfl_xor(f, m, 64);
    }
}

// Parent = 3-way softmax mix of {mean, child0, child1}; 16 lanes / parent.
__device__ __forceinline__ void make_parent4(float4 k0, float4 k1, float4 v0, float4 v1,
                                             float4& kc, float4& vc) {
    float4 kp, vp;
    kp.x = 0.5f * (k0.x + k1.x); kp.y = 0.5f * (k0.y + k1.y);
    kp.z = 0.5f * (k0.z + k1.z); kp.w = 0.5f * (k0.w + k1.w);
    vp.x = 0.5f * (v0.x + v1.x); vp.y = 0.5f * (v0.y + v1.y);
    vp.z = 0.5f * (v0.z + v1.z); vp.w = 0.5f * (v0.w + v1.w);
    float ss = dot4(kp, kp), sa = dot4(kp, k0), sb = dot4(kp, k1);
    reduce3_16(ss, sa, sb);
    ss *= SCALE; sa *= SCALE; sb *= SCALE;
    float mx = fmaxf(ss, fmaxf(sa, sb));
    float es = __expf(ss - mx), ea = __expf(sa - mx), eb = __expf(sb - mx);
    float inv = 1.0f / (es + ea + eb + 1e-9f);
    es *= inv; ea *= inv; eb *= inv;
    kc.x = es * kp.x + ea * k0.x + eb * k1.x;
    kc.y = es * kp.y + ea * k0.y + eb * k1.y;
    kc.z = es * kp.z + ea * k0.z + eb * k1.z;
    kc.w = es * kp.w + ea * k0.w + eb * k1.w;
    vc.x = es * vp.x + ea * v0.x + eb * v1.x;
    vc.y = es * vp.y + ea * v0.y + eb * v1.y;
    vc.z = es * vp.z + ea * v0.z + eb * v1.z;
    vc.w = es * vp.w + ea * v0.w + eb * v1.w;
}

// Two independent sibling mixes with an interleaved 6-value butterfly (ILP).
__device__ __forceinline__ void make_parent_pair4(const float4* k, const float4* v,
                                                  float4& ka, float4& va,
                                                  float4& kb, float4& vb) {
    float4 kpa, vpa, kpb, vpb;
    kpa.x = 0.5f * (k[0].x + k[1].x); kpa.y = 0.5f * (k[0].y + k[1].y);
    kpa.z = 0.5f * (k[0].z + k[1].z); kpa.w = 0.5f * (k[0].w + k[1].w);
    vpa.x = 0.5f * (v[0].x + v[1].x); vpa.y = 0.5f * (v[0].y + v[1].y);
    vpa.z = 0.5f * (v[0].z + v[1].z); vpa.w = 0.5f * (v[0].w + v[1].w);
    kpb.x = 0.5f * (k[2].x + k[3].x); kpb.y = 0.5f * (k[2].y + k[3].y);
    kpb.z = 0.5f * (k[2].z + k[3].z); kpb.w = 0.5f * (k[2].w + k[3].w);
    vpb.x = 0.5f * (v[2].x + v[3].x); vpb.y = 0.5f * (v[2].y + v[3].y);
    vpb.z = 0.5f * (v[2].z + v[3].z); vpb.w = 0.5f * (v[2].w + v[3].w);
    float ssa = dot4(kpa, kpa), saa = dot4(kpa, k[0]), sba = dot4(kpa, k[1]);
    float ssb = dot4(kpb, kpb), sab = dot4(kpb, k[2]), sbb = dot4(kpb, k[3]);
    reduce6_16(ssa, saa, sba, ssb, sab, sbb);
    ssa *= SCALE; saa *= SCALE; sba *= SCALE;
    ssb *= SCALE; sab *= SCALE; sbb *= SCALE;
    float mxa = fmaxf(ssa, fmaxf(saa, sba));
    float mxb = fmaxf(ssb, fmaxf(sab, sbb));
    float esa = __expf(ssa - mxa), eaa = __expf(saa - mxa), eba = __expf(sba - mxa);
    float esb = __expf(ssb - mxb), eab = __expf(sab - mxb), ebb = __expf(sbb - mxb);
    float iva = 1.0f / (esa + eaa + eba + 1e-9f);
    float ivb = 1.0f / (esb + eab + ebb + 1e-9f);
    esa *= iva; eaa *= iva; eba *= iva;
    esb *= ivb; eab *= ivb; ebb *= ivb;
    ka.x = esa * kpa.x + eaa * k[0].x + eba * k[1].x;
    ka.y = esa * kpa.y + eaa * k[0].y + eba * k[1].y;
    ka.z = esa * kpa.z + eaa * k[0].z + eba * k[1].z;
    ka.w = esa * kpa.w + eaa * k[0].w + eba * k[1].w;
    va.x = esa * vpa.x + eaa * v[0].x + eba * v[1].x;
    va.y = esa * vpa.y + eaa * v[0].y + eba * v[1].y;
    va.z = esa * vpa.z + eaa * v[0].z + eba * v[1].z;
    va.w = esa * vpa.w + eaa * v[0].w + eba * v[1].w;
    kb.x = esb * kpb.x + eab * k[2].x + ebb * k[3].x;
    kb.y = esb * kpb.y + eab * k[2].y + ebb * k[3].y;
    kb.z = esb * kpb.z + eab * k[2].z + ebb * k[3].z;
    kb.w = esb * kpb.w + eab * k[2].w + ebb * k[3].w;
    vb.x = esb * vpb.x + eab * v[2].x + ebb * v[3].x;
    vb.y = esb * vpb.y + eab * v[2].y + ebb * v[3].y;
    vb.z = esb * vpb.z + eab * v[2].z + ebb * v[3].z;
    vb.w = esb * vpb.w + eab * v[2].w + ebb * v[3].w;
}

// 4-ary consolidation step: 4 child rows -> 2 parents (stored) + 1 grandparent.
__device__ __forceinline__ void quad_step(const float4* k, const float4* v,
                                          float4* Kw4, float4* Vw4,
                                          size_t pRow0, size_t gRow,   // float4 base offsets (+t)
                                          int t,
                                          float4& kg, float4& vg) {
    float4 ka, va, kb, vb;
    make_parent_pair4(k, v, ka, va, kb, vb);
    Kw4[pRow0 + t] = ka;            Vw4[pRow0 + t] = va;
    Kw4[pRow0 + HSTRIDE + t] = kb;  Vw4[pRow0 + HSTRIDE + t] = vb;
    make_parent4(ka, kb, va, vb, kg, vg);
    Kw4[gRow + t] = kg;             Vw4[gRow + t] = vg;
}

// ---- Kernel A: tree levels 1..6 for one 64-leaf chunk. 1024 blocks (b,h,c).
// 3 rounds of 4-ary consolidation, 2 barriers.
__global__ __launch_bounds__(256) void tree_low(const float* __restrict__ K,
                                                const float* __restrict__ V,
                                                float* __restrict__ Kw,
                                                float* __restrict__ Vw) {
    __shared__ float4 Kb[20 * ROWF4];   // rows [0,16): lvl2 ; rows [16,20): lvl4
    __shared__ float4 Vb[20 * ROWF4];
    const float4* K4 = (const float4*)K;
    const float4* V4 = (const float4*)V;
    float4* Kw4 = (float4*)Kw;
    float4* Vw4 = (float4*)Vw;

    int bid = blockIdx.x;
    int c = bid & 31;
    int h = (bid >> 5) & 15;
    int b = bid >> 9;
    int lane = threadIdx.x & 63;
    int gg = (threadIdx.x >> 6) * 4 + (lane >> 4);   // group 0..15
    int t = lane & 15;

    size_t wsBase = (size_t)(b * WSSLOTS) * HSTRIDE + h * ROWF4;  // + slot*HSTRIDE + t

    // Round A: 16 groups, 4 leaves each -> lvl1 pair + lvl2 node
    {
        int n0 = c * 64 + 4 * gg;
        const float4* Kr = K4 + ((size_t)((b * NSEQ + n0) * HEADS + h)) * ROWF4;
        const float4* Vr = V4 + ((size_t)((b * NSEQ + n0) * HEADS + h)) * ROWF4;
        float4 k[4], v[4];
#pragma unroll
        for (int j = 0; j < 4; ++j) { k[j] = Kr[j * HSTRIDE + t]; v[j] = Vr[j * HSTRIDE + t]; }
        int s1 = c * 32 + 2 * gg;          // lvl1 slots s1, s1+1
        int s2 = 1024 + c * 16 + gg;       // lvl2 slot
        float4 kg, vg;
        quad_step(k, v, Kw4, Vw4, wsBase + (size_t)s1 * HSTRIDE,
                  wsBase + (size_t)s2 * HSTRIDE, t, kg, vg);
        Kb[gg * ROWF4 + t] = kg;  Vb[gg * ROWF4 + t] = vg;
    }
    __syncthreads();
    // Round B: groups 0..3, lvl2 rows -> lvl3 pair + lvl4 node
    if (gg < 4) {
        float4 k[4], v[4];
#pragma unroll
        for (int j = 0; j < 4; ++j) {
            k[j] = Kb[(4 * gg + j) * ROWF4 + t];
            v[j] = Vb[(4 * gg + j) * ROWF4 + t];
        }
        int s3 = 1536 + c * 8 + 2 * gg;
        int s4 = 1792 + c * 4 + gg;
        float4 kg, vg;
        quad_step(k, v, Kw4, Vw4, wsBase + (size_t)s3 * HSTRIDE,
                  wsBase + (size_t)s4 * HSTRIDE, t, kg, vg);
        Kb[(16 + gg) * ROWF4 + t] = kg;  Vb[(16 + gg) * ROWF4 + t] = vg;
    }
    __syncthreads();
    // Round C: group 0, lvl4 rows -> lvl5 pair + lvl6 node
    if (gg == 0) {
        float4 k[4], v[4];
#pragma unroll
        for (int j = 0; j < 4; ++j) {
            k[j] = Kb[(16 + j) * ROWF4 + t];
            v[j] = Vb[(16 + j) * ROWF4 + t];
        }
        int s5 = 1920 + c * 2;
        int s6 = 1984 + c;
        float4 kg, vg;
        quad_step(k, v, Kw4, Vw4, wsBase + (size_t)s5 * HSTRIDE,
                  wsBase + (size_t)s6 * HSTRIDE, t, kg, vg);
    }
}

// ---- Kernel B: tree levels 7..10 for one (b,h). 32 blocks, 2 rounds, 1 barrier.
__global__ __launch_bounds__(256) void tree_top(float* __restrict__ Kw,
                                                float* __restrict__ Vw) {
    __shared__ float4 Kb[8 * ROWF4];    // lvl8 nodes
    __shared__ float4 Vb[8 * ROWF4];
    float4* Kw4 = (float4*)Kw;
    float4* Vw4 = (float4*)Vw;

    int h = blockIdx.x & 15, b = blockIdx.x >> 4;
    int lane = threadIdx.x & 63;
    int gg = (threadIdx.x >> 6) * 4 + (lane >> 4);
    int t = lane & 15;
    size_t wsBase = (size_t)(b * WSSLOTS) * HSTRIDE + h * ROWF4;

    // Round A: groups 0..7: 4 lvl6 rows -> lvl7 pair + lvl8 node
    if (gg < 8) {
        float4 k[4], v[4];
#pragma unroll
        for (int j = 0; j < 4; ++j) {
            size_t r = wsBase + (size_t)(1984 + 4 * gg + j) * HSTRIDE + t;
            k[j] = Kw4[r]; v[j] = Vw4[r];
        }
        int s7 = 2016 + 2 * gg;
        int s8 = 2032 + gg;
        float4 kg, vg;
        quad_step(k, v, Kw4, Vw4, wsBase + (size_t)s7 * HSTRIDE,
                  wsBase + (size_t)s8 * HSTRIDE, t, kg, vg);
        Kb[gg * ROWF4 + t] = kg;  Vb[gg * ROWF4 + t] = vg;
    }
    __syncthreads();
    // Round B: groups 0..1: 4 lvl8 rows -> lvl9 pair + lvl10 node
    if (gg < 2) {
        float4 k[4], v[4];
#pragma unroll
        for (int j = 0; j < 4; ++j) {
            k[j] = Kb[(4 * gg + j) * ROWF4 + t];
            v[j] = Vb[(4 * gg + j) * ROWF4 + t];
        }
        int s9  = 2040 + 2 * gg;
        int s10 = 2044 + gg;
        float4 kg, vg;
        quad_step(k, v, Kw4, Vw4, wsBase + (size_t)s9 * HSTRIDE,
                  wsBase + (size_t)s10 * HSTRIDE, t, kg, vg);
    }
}

// ---- Kernel C: attention. One wave = 4 heads of one (b,n). 4096 blocks.
// Masked columns have weight exactly 0 -> skip their K/V loads, dots, and
// V-accumulation entirely (mask is wave-uniform: same n across the wave).
// Butterfly reduction stays unconditional over 12 (zeros reduce fine;
// interleaved 4-deep chains pipeline better than 12 conditional reductions).
__global__ __launch_bounds__(256) void attn(const float* __restrict__ Q,
                                            const float* __restrict__ K,
                                            const float* __restrict__ V,
                                            const float* __restrict__ Kw,
                                            const float* __restrict__ Vw,
                                            float* __restrict__ out) {
    const float4* Q4 = (const float4*)Q;
    const float4* K4 = (const float4*)K;
    const float4* V4 = (const float4*)V;
    const float4* Kw4 = (const float4*)Kw;
    const float4* Vw4 = (const float4*)Vw;
    float4* O4 = (float4*)out;

    int bid = blockIdx.x;                              // 0..4095
    int vbid = ((bid & 7) << 9) | (bid >> 3);          // bijective XCD remap
    int w = vbid * 4 + (threadIdx.x >> 6);             // wave id over B*N*(H/4)
    int lane = threadIdx.x & 63;
    int g = lane >> 4;
    int t = lane & 15;
    int h = (w & 3) * 4 + g;
    int n = (w >> 2) & (NSEQ - 1);
    int b = w >> 13;

    int row0 = (b * NSEQ + n) * HSTRIDE;               // self leaf / Q / out
    int row1 = (b * NSEQ + (n ^ 1)) * HSTRIDE;         // sibling leaf
    int rowt[10];
#pragma unroll
    for (int l = 2; l < 12; ++l) {
        int j = l - 1;
        int slot = level_offset(j) - NSEQ + ((n >> j) ^ 1);
        rowt[l - 2] = (b * WSSLOTS + slot) * HSTRIDE;
    }
    int hoff = h * ROWF4 + t;

    // column l active iff l==0 or bit (l-1) of n set (wave-uniform)
    unsigned active = 1u | (((unsigned)n & 0x7FFu) << 1);

    float4 q4 = Q4[row0 + hoff];

    // Load + dot + V-load only for active columns (uniform branches).
    float4 k[12], v[12];
    float s[12];
    k[0] = K4[row0 + hoff];
    v[0] = V4[row0 + hoff];
    if (active & 2u) { k[1] = K4[row1 + hoff]; v[1] = V4[row1 + hoff]; }
#pragma unroll
    for (int l = 2; l < 12; ++l) {
        if (active & (1u << l)) {
            k[l] = Kw4[rowt[l - 2] + hoff];
            v[l] = Vw4[rowt[l - 2] + hoff];
        }
    }
    s[0] = dot4(q4, k[0]);
#pragma unroll
    for (int l = 1; l < 12; ++l)
        s[l] = (active & (1u << l)) ? dot4(q4, k[l]) : 0.f;

#pragma unroll
    for (int m = 1; m < 16; m <<= 1) {
#pragma unroll
        for (int l = 0; l < 12; ++l) s[l] += __shfl_xor(s[l], m, 64);
    }

    float mx = -3.402823466e+38f;
#pragma unroll
    for (int l = 0; l < 12; ++l) {
        s[l] *= SCALE;
        if (active & (1u << l)) mx = fmaxf(mx, s[l]);
    }
    float sum = 0.f;
#pragma unroll
    for (int l = 0; l < 12; ++l) {
        float e = (active & (1u << l)) ? __expf(s[l] - mx) : 0.f;
        s[l] = e;
        sum += e;
    }
    float inv = 1.0f / sum;

    float4 o = make_float4(0.f, 0.f, 0.f, 0.f);
    o.x += s[0] * v[0].x; o.y += s[0] * v[0].y;
    o.z += s[0] * v[0].z; o.w += s[0] * v[0].w;
#pragma unroll
    for (int l = 1; l < 12; ++l) {
        if (active & (1u << l)) {
            o.x += s[l] * v[l].x; o.y += s[l] * v[l].y;
            o.z += s[l] * v[l].z; o.w += s[l] * v[l].w;
        }
    }
    O4[row0 + hoff] = make_float4(o.x * inv, o.y * inv, o.z * inv, o.w * inv);
}

extern "C" void kernel_launch(void* const* d_in, const int* in_sizes, int n_in,
                              void* d_out, int out_size, void* d_ws, size_t ws_size,
                              hipStream_t stream) {
    const float* Q = (const float*)d_in[0];
    const float* K = (const float*)d_in[1];
    const float* V = (const float*)d_in[2];
    float* out = (float*)d_out;
    float* Kw = (float*)d_ws;              // 16.78 MiB
    float* Vw = Kw + WSELEMS;              // 16.78 MiB

    tree_low<<<1024, 256, 0, stream>>>(K, V, Kw, Vw);
    tree_top<<<BATCH * HEADS, 256, 0, stream>>>(Kw, Vw);
    attn<<<(BATCH * NSEQ * (HEADS / 4)) / 4, 256, 0, stream>>>(Q, K, V, Kw, Vw, out);
}